// Round 3
// baseline (151.598 us; speedup 1.0000x reference)
//
#include <hip/hip_runtime.h>
#include <math.h>

// Problem constants (fixed by the reference)
#define BG 64            // graphs
#define NN 2048          // nodes per graph
#define HH 64            // hidden dim
#define NHD 4            // heads
#define DHD 16           // head dim
#define MM (3*NN)        // 6144 framelet rows
#define EE (8*MM)        // 49152 nnz per graph
#define SLICES 8         // E-slices per graph (pass A)
#define EPB (EE/SLICES)  // 6144 entries per pass-A block
#define KS 8             // K-split blocks per graph (pass B)
#define NPB (NN/KS)      // 256 nodes per pass-B block

// ---------------- Pass A: wsum[b][g][n] = sum of vals with col n, group g ----
// One block per (graph, E-slice). LDS accumulate (float atomics), then write
// the slice-partial wsum to workspace (no global atomics, no pre-zeroing).
__global__ __launch_bounds__(256) void passA_kernel(
        const int* __restrict__ d_rows, const int* __restrict__ d_cols,
        const float* __restrict__ d_vals, const int* __restrict__ d_index,
        float* __restrict__ part_wsum) {
    __shared__ float w[3 * NN];                    // 24 KB
    const int b = blockIdx.x / SLICES;
    const int s = blockIdx.x % SLICES;
    const int tid = threadIdx.x;

    for (int i = tid; i < 3 * NN; i += 256) w[i] = 0.0f;
    __syncthreads();

    const size_t base = (size_t)b * EE + (size_t)s * EPB;   // 16B-aligned
    const int4*   rows4 = (const int4*)(d_rows + base);
    const int4*   cols4 = (const int4*)(d_cols + base);
    const float4* vals4 = (const float4*)(d_vals + base);
    const int* dib = d_index + (size_t)b * MM;

#pragma unroll
    for (int it = 0; it < EPB / 4 / 256; ++it) {   // 6 iterations
        const int idx = it * 256 + tid;
        int4   r = rows4[idx];
        int4   c = cols4[idx];
        float4 v = vals4[idx];
        int g0 = dib[r.x], g1 = dib[r.y], g2 = dib[r.z], g3 = dib[r.w];
        atomicAdd(&w[g0 * NN + c.x], v.x);
        atomicAdd(&w[g1 * NN + c.y], v.y);
        atomicAdd(&w[g2 * NN + c.z], v.z);
        atomicAdd(&w[g3 * NN + c.w], v.w);
    }
    __syncthreads();

    float* out = part_wsum + ((size_t)b * SLICES + s) * (3 * NN);
    for (int i = tid; i < 3 * NN; i += 256) out[i] = w[i];
}

// ---------------- Pass B: pool_part[b][ks][g][h] = wred[g][n] @ x[b][n][h] ---
// One block per (graph, node-slice). Reduce the SLICES wsum partials into LDS,
// then a tiny dense GEMM over the node slice; x read exactly once grid-wide.
__global__ __launch_bounds__(192) void passB_kernel(
        const float* __restrict__ x, const float* __restrict__ part_wsum,
        float* __restrict__ part_pool) {
    __shared__ float wred[3 * NPB];                // 3 KB
    const int b  = blockIdx.x / KS;
    const int ks = blockIdx.x % KS;
    const int tid = threadIdx.x;                   // 192 threads

    // reduce slice partials for this node range: wred[g][n]
    for (int i = tid; i < 3 * NPB; i += 192) {
        const int g = i / NPB, n = i % NPB;
        const float* src = part_wsum + (size_t)b * SLICES * (3 * NN)
                         + (size_t)g * NN + (size_t)ks * NPB + n;
        float v = 0.0f;
#pragma unroll
        for (int s = 0; s < SLICES; ++s) v += src[(size_t)s * (3 * NN)];
        wred[i] = v;
    }
    __syncthreads();

    const int g = tid >> 6, h = tid & 63;
    const float* xb = x + ((size_t)b * NN + (size_t)ks * NPB) * HH + h;
    const float* wg = wred + g * NPB;
    float acc = 0.0f;
#pragma unroll 8
    for (int n = 0; n < NPB; ++n) {
        acc += wg[n] * xb[(size_t)n * HH];
    }
    part_pool[(((size_t)b * KS + ks) * 3 + g) * HH + h] = acc;
}

// ---------------- Pass C: tiny 3-token multi-head attention per graph -------
__global__ __launch_bounds__(192) void passC_kernel(
        const float* __restrict__ part_pool,
        const float* __restrict__ Wq, const float* __restrict__ Wk,
        const float* __restrict__ Wv, float* __restrict__ out) {
    __shared__ float p[3][HH];                     // pooled [3][64]
    __shared__ float Wl[3][HH][HH + 1];            // padded
    __shared__ float Ql[3][HH], Kl[3][HH], Vl[3][HH];
    const int b = blockIdx.x;
    const int tid = threadIdx.x;                   // 192
    const int q = tid >> 6, h = tid & 63;

    // reduce pool partials
    float pv = 0.0f;
#pragma unroll
    for (int s = 0; s < KS; ++s)
        pv += part_pool[(((size_t)b * KS + s) * 3 + q) * HH + h];
    p[q][h] = pv;

    // stage the three weight matrices (row-major [h][k], padded)
    for (int i = tid; i < 3 * HH * HH; i += 192) {
        const int m = i >> 12;                     // 4096 elems per matrix
        const int rem = i & 4095;
        const int r = rem >> 6, c = rem & 63;
        const float* Wsrc = (m == 0) ? Wq : (m == 1) ? Wk : Wv;
        Wl[m][r][c] = Wsrc[rem];
    }
    __syncthreads();

    // Q[q][h] = sum_k p[q][k] * W[h][k]   (y = x @ W^T)
    float accq = 0.0f, acck = 0.0f, accv = 0.0f;
#pragma unroll
    for (int k = 0; k < HH; ++k) {
        const float pk = p[q][k];
        accq += pk * Wl[0][h][k];
        acck += pk * Wl[1][h][k];
        accv += pk * Wl[2][h][k];
    }
    Ql[q][h] = accq; Kl[q][h] = acck; Vl[q][h] = accv;
    __syncthreads();

    // scores over 3 keys for this (q, head) ; NORM = 1/sqrt(16) = 0.25
    const int nh = h >> 4;
    float s0 = 0.0f, s1 = 0.0f, s2 = 0.0f;
#pragma unroll
    for (int d = 0; d < DHD; ++d) {
        const float qq = Ql[q][nh * DHD + d];
        s0 += qq * Kl[0][nh * DHD + d];
        s1 += qq * Kl[1][nh * DHD + d];
        s2 += qq * Kl[2][nh * DHD + d];
    }
    s0 *= 0.25f; s1 *= 0.25f; s2 *= 0.25f;
    const float mx = fmaxf(s0, fmaxf(s1, s2));
    const float e0 = expf(s0 - mx), e1 = expf(s1 - mx), e2 = expf(s2 - mx);
    const float inv = 1.0f / (e0 + e1 + e2);
    const float av = (e0 * Vl[0][h] + e1 * Vl[1][h] + e2 * Vl[2][h]) * inv;

    out[(size_t)b * (3 * HH) + (size_t)q * HH + h] = av;
}

extern "C" void kernel_launch(void* const* d_in, const int* in_sizes, int n_in,
                              void* d_out, int out_size, void* d_ws, size_t ws_size,
                              hipStream_t stream) {
    const float* x      = (const float*)d_in[0];
    // d_in[1] = batch (unused; fixed N nodes/graph), d_in[2] = batch_size (fixed 64)
    const int*   d_rows = (const int*)d_in[3];
    const int*   d_cols = (const int*)d_in[4];
    const float* d_vals = (const float*)d_in[5];
    const int*   d_index= (const int*)d_in[6];
    const float* Wq     = (const float*)d_in[7];
    const float* Wk     = (const float*)d_in[8];
    const float* Wv     = (const float*)d_in[9];
    float* out = (float*)d_out;

    // workspace layout (all fully written before read; no zeroing needed):
    //   part_wsum: B*SLICES*3*N floats = 12.58 MB
    //   part_pool: B*KS*3*H floats     = 0.39 MB
    float* part_wsum = (float*)d_ws;
    float* part_pool = part_wsum + (size_t)BG * SLICES * 3 * NN;

    passA_kernel<<<BG * SLICES, 256, 0, stream>>>(d_rows, d_cols, d_vals,
                                                  d_index, part_wsum);
    passB_kernel<<<BG * KS, 192, 0, stream>>>(x, part_wsum, part_pool);
    passC_kernel<<<BG, 192, 0, stream>>>(part_pool, Wq, Wk, Wv, out);
}

// Round 4
// 146.061 us; speedup vs baseline: 1.0379x; 1.0379x over previous
//
#include <hip/hip_runtime.h>
#include <math.h>

// Problem constants (fixed by the reference)
#define BG 64            // graphs
#define NN 2048          // nodes per graph
#define HH 64            // hidden dim
#define NHD 4            // heads
#define DHD 16           // head dim
#define MM (3*NN)        // 6144 framelet rows
#define EE (8*MM)        // 49152 nnz per graph
#define SLICES 8         // E-slices per graph (pass A)
#define EPB (EE/SLICES)  // 6144 entries per pass-A block
#define KS 8             // K-split blocks per graph (pass B)
#define NPB (NN/KS)      // 256 nodes per pass-B block

// ---------------- Pass A: wsum[b][g][n] = sum of vals with col n, group g ----
// One block per (graph, E-slice). d_index staged in LDS so the per-entry
// row->group gather is an LDS read (~2-way bank alias, near-free) instead of
// a 64-way-divergent L1 gather (64 serialized transactions per instr).
__global__ __launch_bounds__(256) void passA_kernel(
        const int* __restrict__ d_rows, const int* __restrict__ d_cols,
        const float* __restrict__ d_vals, const int* __restrict__ d_index,
        float* __restrict__ part_wsum) {
    __shared__ float w[3 * NN];                    // 24 KB
    __shared__ int   gidx[MM];                     // 24 KB (row -> group)
    const int b = blockIdx.x / SLICES;
    const int s = blockIdx.x % SLICES;
    const int tid = threadIdx.x;

    // coalesced stage of d_index[b][:] into LDS + zero the accumulator
    const int4* di4 = (const int4*)(d_index + (size_t)b * MM);
    for (int i = tid; i < MM / 4; i += 256) ((int4*)gidx)[i] = di4[i];
    for (int i = tid; i < 3 * NN; i += 256) w[i] = 0.0f;
    __syncthreads();

    const size_t base = (size_t)b * EE + (size_t)s * EPB;   // 16B-aligned
    const int4*   rows4 = (const int4*)(d_rows + base);
    const int4*   cols4 = (const int4*)(d_cols + base);
    const float4* vals4 = (const float4*)(d_vals + base);

#pragma unroll
    for (int it = 0; it < EPB / 4 / 256; ++it) {   // 6 iterations
        const int idx = it * 256 + tid;
        int4   r = rows4[idx];
        int4   c = cols4[idx];
        float4 v = vals4[idx];
        int g0 = gidx[r.x], g1 = gidx[r.y], g2 = gidx[r.z], g3 = gidx[r.w];
        atomicAdd(&w[g0 * NN + c.x], v.x);
        atomicAdd(&w[g1 * NN + c.y], v.y);
        atomicAdd(&w[g2 * NN + c.z], v.z);
        atomicAdd(&w[g3 * NN + c.w], v.w);
    }
    __syncthreads();

    float* out = part_wsum + ((size_t)b * SLICES + s) * (3 * NN);
    for (int i = tid; i < 3 * NN; i += 256) out[i] = w[i];
}

// ---------------- Pass B: pool_part[b][ks][g][h] = wred[g][n] @ x[b][n][h] ---
// One block per (graph, node-slice), 256 threads (4 waves). Each thread keeps
// all 3 group accumulators (3 FMA per x-load); nodes strided across waves;
// wred[] reads are wave-uniform broadcasts (free). Cross-wave LDS reduce.
__global__ __launch_bounds__(256) void passB_kernel(
        const float* __restrict__ x, const float* __restrict__ part_wsum,
        float* __restrict__ part_pool) {
    __shared__ float wred[3 * NPB];                // 3 KB
    __shared__ float red[4][3][HH];                // 3 KB
    const int b  = blockIdx.x / KS;
    const int ks = blockIdx.x % KS;
    const int tid = threadIdx.x;                   // 256 threads

    // reduce slice partials for this node range: wred[g][n]
    for (int i = tid; i < 3 * NPB; i += 256) {
        const int g = i / NPB, n = i % NPB;
        const float* src = part_wsum + (size_t)b * SLICES * (3 * NN)
                         + (size_t)g * NN + (size_t)ks * NPB + n;
        float v = 0.0f;
#pragma unroll
        for (int s = 0; s < SLICES; ++s) v += src[(size_t)s * (3 * NN)];
        wred[i] = v;
    }
    __syncthreads();

    const int w = tid >> 6, h = tid & 63;
    const float* xb = x + ((size_t)b * NN + (size_t)ks * NPB) * HH + h;
    float a0 = 0.0f, a1 = 0.0f, a2 = 0.0f;
#pragma unroll 4
    for (int n = w; n < NPB; n += 4) {             // 64 iters/thread
        const float xv = xb[(size_t)n * HH];
        a0 += wred[0 * NPB + n] * xv;              // wave-uniform broadcast
        a1 += wred[1 * NPB + n] * xv;
        a2 += wred[2 * NPB + n] * xv;
    }
    red[w][0][h] = a0; red[w][1][h] = a1; red[w][2][h] = a2;
    __syncthreads();

    if (tid < 3 * HH) {
        const int g = tid >> 6, h2 = tid & 63;
        const float v = red[0][g][h2] + red[1][g][h2]
                      + red[2][g][h2] + red[3][g][h2];
        part_pool[(((size_t)b * KS + ks) * 3 + g) * HH + h2] = v;
    }
}

// ---------------- Pass C: tiny 3-token multi-head attention per graph -------
__global__ __launch_bounds__(192) void passC_kernel(
        const float* __restrict__ part_pool,
        const float* __restrict__ Wq, const float* __restrict__ Wk,
        const float* __restrict__ Wv, float* __restrict__ out) {
    __shared__ float p[3][HH];                     // pooled [3][64]
    __shared__ float Wl[3][HH][HH + 1];            // padded
    __shared__ float Ql[3][HH], Kl[3][HH], Vl[3][HH];
    const int b = blockIdx.x;
    const int tid = threadIdx.x;                   // 192
    const int q = tid >> 6, h = tid & 63;

    // reduce pool partials
    float pv = 0.0f;
#pragma unroll
    for (int s = 0; s < KS; ++s)
        pv += part_pool[(((size_t)b * KS + s) * 3 + q) * HH + h];
    p[q][h] = pv;

    // stage the three weight matrices (row-major [h][k], padded)
    for (int i = tid; i < 3 * HH * HH; i += 192) {
        const int m = i >> 12;                     // 4096 elems per matrix
        const int rem = i & 4095;
        const int r = rem >> 6, c = rem & 63;
        const float* Wsrc = (m == 0) ? Wq : (m == 1) ? Wk : Wv;
        Wl[m][r][c] = Wsrc[rem];
    }
    __syncthreads();

    // Q[q][h] = sum_k p[q][k] * W[h][k]   (y = x @ W^T)
    float accq = 0.0f, acck = 0.0f, accv = 0.0f;
#pragma unroll
    for (int k = 0; k < HH; ++k) {
        const float pk = p[q][k];
        accq += pk * Wl[0][h][k];
        acck += pk * Wl[1][h][k];
        accv += pk * Wl[2][h][k];
    }
    Ql[q][h] = accq; Kl[q][h] = acck; Vl[q][h] = accv;
    __syncthreads();

    // scores over 3 keys for this (q, head) ; NORM = 1/sqrt(16) = 0.25
    const int nh = h >> 4;
    float s0 = 0.0f, s1 = 0.0f, s2 = 0.0f;
#pragma unroll
    for (int d = 0; d < DHD; ++d) {
        const float qq = Ql[q][nh * DHD + d];
        s0 += qq * Kl[0][nh * DHD + d];
        s1 += qq * Kl[1][nh * DHD + d];
        s2 += qq * Kl[2][nh * DHD + d];
    }
    s0 *= 0.25f; s1 *= 0.25f; s2 *= 0.25f;
    const float mx = fmaxf(s0, fmaxf(s1, s2));
    const float e0 = expf(s0 - mx), e1 = expf(s1 - mx), e2 = expf(s2 - mx);
    const float inv = 1.0f / (e0 + e1 + e2);
    const float av = (e0 * Vl[0][h] + e1 * Vl[1][h] + e2 * Vl[2][h]) * inv;

    out[(size_t)b * (3 * HH) + (size_t)q * HH + h] = av;
}

extern "C" void kernel_launch(void* const* d_in, const int* in_sizes, int n_in,
                              void* d_out, int out_size, void* d_ws, size_t ws_size,
                              hipStream_t stream) {
    const float* x      = (const float*)d_in[0];
    // d_in[1] = batch (unused; fixed N nodes/graph), d_in[2] = batch_size (fixed 64)
    const int*   d_rows = (const int*)d_in[3];
    const int*   d_cols = (const int*)d_in[4];
    const float* d_vals = (const float*)d_in[5];
    const int*   d_index= (const int*)d_in[6];
    const float* Wq     = (const float*)d_in[7];
    const float* Wk     = (const float*)d_in[8];
    const float* Wv     = (const float*)d_in[9];
    float* out = (float*)d_out;

    // workspace layout (all fully written before read; no zeroing needed):
    //   part_wsum: B*SLICES*3*N floats = 12.58 MB
    //   part_pool: B*KS*3*H floats     = 0.39 MB
    float* part_wsum = (float*)d_ws;
    float* part_pool = part_wsum + (size_t)BG * SLICES * 3 * NN;

    passA_kernel<<<BG * SLICES, 256, 0, stream>>>(d_rows, d_cols, d_vals,
                                                  d_index, part_wsum);
    passB_kernel<<<BG * KS, 256, 0, stream>>>(x, part_wsum, part_pool);
    passC_kernel<<<BG, 192, 0, stream>>>(part_pool, Wq, Wk, Wv, out);
}